// Round 3
// 1145.465 us; speedup vs baseline: 1.0388x; 1.0388x over previous
//
#include <hip/hip_runtime.h>
#include <hip/hip_bf16.h>
#include <hip/hip_fp16.h>

// Problem: B=64, S=512, E=768, H=256 (4H=1024). Bidirectional relu-LSTM + dense(2).
#define B_ 64
#define S_ 512
#define E_ 768
#define H_ 256
#define G_ 1024  // 4H
#define MROWS 32768  // B*S per direction

typedef float f32x4 __attribute__((ext_vector_type(4)));
typedef float f32x16 __attribute__((ext_vector_type(16)));
typedef short short8 __attribute__((ext_vector_type(8)));
typedef _Float16 v2h __attribute__((ext_vector_type(2)));
typedef unsigned int u32x4 __attribute__((ext_vector_type(4)));

// ---------------- prep kernels ----------------

__global__ void cast_x_kernel(const float* __restrict__ x, __hip_bfloat16* __restrict__ xbf, int n) {
    int i = (blockIdx.x * 256 + threadIdx.x) * 4;
    if (i >= n) return;
    float4 v = *(const float4*)(x + i);
    xbf[i + 0] = __float2bfloat16(v.x);
    xbf[i + 1] = __float2bfloat16(v.y);
    xbf[i + 2] = __float2bfloat16(v.z);
    xbf[i + 3] = __float2bfloat16(v.w);
}

// kernel [E][G] fp32 -> kT [dir][G][E] bf16 (transposed for MFMA B-fragments)
__global__ void prep_kT_kernel(const float* __restrict__ kf, const float* __restrict__ kb,
                               __hip_bfloat16* __restrict__ kT) {
    int idx = blockIdx.x * 256 + threadIdx.x;   // over E_*G_
    int dir = blockIdx.y;
    const float* src = dir ? kb : kf;
    int k = idx >> 10;        // E index
    int n = idx & 1023;       // G index
    float v = src[idx];       // coalesced read (n fast)
    kT[(size_t)dir * G_ * E_ + (size_t)n * E_ + k] = __float2bfloat16(v);
}

// rec [256][1024] fp32 -> recQ [dir][32][1024] uint4: half2 pairs of k = 8kk..8kk+7, col g
__global__ void prep_recQ_kernel(const float* __restrict__ rf, const float* __restrict__ rb,
                                 unsigned int* __restrict__ recQ) {
    int idx = blockIdx.x * 256 + threadIdx.x;   // over 32*1024*4 = 131072
    int dir = blockIdx.y;
    const float* src = dir ? rb : rf;
    int g  = idx & 1023;
    int u  = (idx >> 10) & 3;
    int kk = idx >> 12;
    int k0 = 8 * kk + 2 * u;
    float a = src[(size_t)k0 * G_ + g];
    float b = src[(size_t)(k0 + 1) * G_ + g];
    v2h p;
    p[0] = (_Float16)a;
    p[1] = (_Float16)b;
    recQ[(size_t)dir * 131072 + (size_t)kk * 4096 + g * 4 + u] = __builtin_bit_cast(unsigned int, p);
}

// ---------------- xz GEMM: LDS-tiled 128x128, BK=32, mfma 32x32x16 (unchanged) --------
#define TM 128
#define TN 128
#define BK 32
#define LDA 40   // padded LDS row stride in elements

__global__ __launch_bounds__(256) void gemm_xz_kernel(
        const __hip_bfloat16* __restrict__ xbf,   // [B*S][E]
        const __hip_bfloat16* __restrict__ kT,    // [2][G][E]
        const float* __restrict__ bias_f, const float* __restrict__ bias_b,
        __hip_bfloat16* __restrict__ xz) {        // [2][MROWS][G]
    int dir  = blockIdx.z;
    int nblk = blockIdx.x;      // 0..7   (G/128)
    int mblk = blockIdx.y;      // 0..255 (MROWS/128)
    int tid  = threadIdx.x;
    int wave = tid >> 6, lane = tid & 63;

    __shared__ __hip_bfloat16 shA[TM * LDA];
    __shared__ __hip_bfloat16 shB[TN * LDA];

    int m0 = mblk * TM;
    int n0 = nblk * TN;

    int rowl0 = tid >> 2;             // 0..63
    int rowl1 = rowl0 + 64;           // 64..127
    int k8    = (tid & 3) * 8;
    int ar0 = m0 + rowl0, ar1 = m0 + rowl1;
    int sa0 = (ar0 & ~511) | (dir ? (511 - (ar0 & 511)) : (ar0 & 511));
    int sa1 = (ar1 & ~511) | (dir ? (511 - (ar1 & 511)) : (ar1 & 511));
    const __hip_bfloat16* kbase = kT + (size_t)dir * G_ * E_;

    f32x16 acc[4] = {};

    int lm = lane & 31;
    int kq = (lane >> 5) * 8;

    for (int k0 = 0; k0 < E_; k0 += BK) {
        __syncthreads();
        *(short8*)&shA[rowl0 * LDA + k8] = *(const short8*)(xbf + (size_t)sa0 * E_ + k0 + k8);
        *(short8*)&shA[rowl1 * LDA + k8] = *(const short8*)(xbf + (size_t)sa1 * E_ + k0 + k8);
        *(short8*)&shB[rowl0 * LDA + k8] = *(const short8*)(kbase + (size_t)(n0 + rowl0) * E_ + k0 + k8);
        *(short8*)&shB[rowl1 * LDA + k8] = *(const short8*)(kbase + (size_t)(n0 + rowl1) * E_ + k0 + k8);
        __syncthreads();

#pragma unroll
        for (int kk = 0; kk < BK; kk += 16) {
            short8 afrag = *(const short8*)&shA[(wave * 32 + lm) * LDA + kk + kq];
#pragma unroll
            for (int j = 0; j < 4; ++j) {
                short8 bfrag = *(const short8*)&shB[(j * 32 + lm) * LDA + kk + kq];
                acc[j] = __builtin_amdgcn_mfma_f32_32x32x16_bf16(afrag, bfrag, acc[j], 0, 0, 0);
            }
        }
    }

    const float* bias = dir ? bias_b : bias_f;
#pragma unroll
    for (int j = 0; j < 4; ++j) {
        int col = n0 + j * 32 + lm;
        float bv = bias[col];
#pragma unroll
        for (int reg = 0; reg < 16; ++reg) {
            int row = m0 + wave * 32 + (reg & 3) + 8 * (reg >> 2) + 4 * (lane >> 5);
            xz[((size_t)dir * MROWS + row) * G_ + col] = __float2bfloat16(acc[j][reg] + bv);
        }
    }
}

// ---------------- recurrent scan ----------------
__device__ inline float dot2f16(unsigned int rbits, unsigned int hbits, float acc) {
#if __has_builtin(__builtin_amdgcn_fdot2)
    return __builtin_amdgcn_fdot2(__builtin_bit_cast(v2h, rbits),
                                  __builtin_bit_cast(v2h, hbits), acc, false);
#else
    v2h r = __builtin_bit_cast(v2h, rbits);
    v2h h = __builtin_bit_cast(v2h, hbits);
    return acc + (float)r[0] * (float)h[0] + (float)r[1] * (float)h[1];
#endif
}

__device__ inline float sigmoidf(float x) { return 1.f / (1.f + __expf(-x)); }

// r8: r5's proven resource profile (512 threads = 8 waves, 48 asm-preloaded rec
// quads = 192 VGPRs/thread, 128 KB rec LDS), but restructured gate ownership so
// each step needs ONE __syncthreads() and NO sh_z exchange:
//   lane lm=lane&31, hi=lane>>5; thread owns h-column col=wave*32+lm.
//   hi=0 lanes accumulate gates (i,f) of col; hi=1 lanes gates (c,o) of the SAME
//   col. The z-exchange is two __shfl_xor(z,32) — register-only, no barrier.
//   Both halves redundantly compute identical c/h; hi=0 writes sh_h[next].
// xz/Wd prefetch for step s+1 is issued (plain C++ loads, compiler-tracked regs)
// at the TOP of step s — the whole dot phase covers the latency, and
// __syncthreads()'s drain lands after it is already complete.
// Only asm: the r5-proven rec preload (48 outstanding loads <= vmcnt max 63).
#define KKREG 24   // kk-groups (8 k each) in VGPRs: 24*2 cols = 48 uint4 = 192 VGPRs
#define KKLDS 8    // kk-groups in LDS: 8 * 16 KB = 128 KB
__global__ __launch_bounds__(512) void scan_kernel(
        const __hip_bfloat16* __restrict__ xz,    // [2][MROWS][G]
        const uint4* __restrict__ recQ,           // [2][32][1024] uint4
        const float* __restrict__ Wd,             // [S*H][2]
        const float* __restrict__ bd,             // [2]
        float* __restrict__ out) {                // [B][2], pre-zeroed
    int b = blockIdx.x, dir = blockIdx.y, tid = threadIdx.x;
    __shared__ __align__(16) uint4 sh_rec[KKLDS * G_];   // 131072 B
    __shared__ __align__(16) _Float16 sh_h[2][H_];       // 1 KB, double-buffered h
    __shared__ float rbuf[16];

    int w = tid >> 6, lane = tid & 63, lm = lane & 31, hi = lane >> 5;
    int col = w * 32 + lm;       // h column 0..255
    int g0  = col + hi * 512;    // gate col: i (hi=0) or c (hi=1)
    int g1  = g0 + 256;          // gate col: f (hi=0) or o (hi=1)

    const uint4* rqbase = recQ + (size_t)dir * 32768;

    // ---- asm-origin preload of rec kk=0..23 for cols g0,g1 (cannot be sunk) ----
    u32x4 rr0[KKREG], rr1[KKREG];
    {
        unsigned long long a0 = (unsigned long long)(const void*)(rqbase + g0);
        unsigned long long a1 = (unsigned long long)(const void*)(rqbase + g1);
#pragma unroll
        for (int kk = 0; kk < KKREG; ++kk) {
            unsigned long long ka0 = a0 + (unsigned long long)kk * 16384ull;
            unsigned long long ka1 = a1 + (unsigned long long)kk * 16384ull;
            asm volatile("global_load_dwordx4 %0, %1, off" : "=v"(rr0[kk]) : "v"(ka0));
            asm volatile("global_load_dwordx4 %0, %1, off" : "=v"(rr1[kk]) : "v"(ka1));
        }
        asm volatile("s_waitcnt vmcnt(0)" ::: "memory");
    }

    // ---- stage rec kk=24..31 (all 1024 cols) into LDS, coalesced ----
#pragma unroll
    for (int j = 0; j < KKLDS * 2; ++j)
        sh_rec[j * 512 + tid] = rqbase[KKREG * 1024 + j * 512 + tid];

    if (tid < H_) sh_h[0][tid] = (_Float16)0.f;
    float c = 0.f, pl0 = 0.f, pl1 = 0.f;
    float wsel = hi ? 0.f : 1.f;
    const __hip_bfloat16* xrb = xz + ((size_t)dir * MROWS + (size_t)b * S_) * G_;
    __syncthreads();

    // prefetch step 0's xz/Wd (plain loads, compiler-tracked)
    float nxz0 = __bfloat162float(xrb[g0]);
    float nxz1 = __bfloat162float(xrb[g1]);
    int t0i = dir ? (S_ - 1) : 0;
    float2 nwv = ((const float2*)Wd)[t0i * H_ + col];

    int p = 0;
    for (int s = 0; s < S_; ++s) {
        // consume prefetched values for this step
        float xz0 = nxz0, xz1 = nxz1;
        float2 wv = nwv;

        // issue prefetch for s+1 NOW: the whole dot phase covers its latency
        int sn = (s + 1 < S_) ? (s + 1) : (S_ - 1);
        int tn = dir ? (S_ - 1 - sn) : sn;
        nxz0 = __bfloat162float(xrb[(size_t)sn * G_ + g0]);
        nxz1 = __bfloat162float(xrb[(size_t)sn * G_ + g1]);
        nwv  = ((const float2*)Wd)[tn * H_ + col];

        const uint4* hp = (const uint4*)&sh_h[p][0];          // 32 uint4 = 256 halves
        float z0a = 0.f, z0b = 0.f, z1a = 0.f, z1b = 0.f;

        // register part (kk 0..23): rec from VGPR, h broadcast from LDS
#pragma unroll
        for (int kk = 0; kk < KKREG; ++kk) {
            uint4 hv = hp[kk];                                 // wave-uniform broadcast
            u32x4 r0 = rr0[kk];
            u32x4 r1 = rr1[kk];
            z0a = dot2f16(r0.x, hv.x, z0a); z0b = dot2f16(r0.y, hv.y, z0b);
            z0a = dot2f16(r0.z, hv.z, z0a); z0b = dot2f16(r0.w, hv.w, z0b);
            z1a = dot2f16(r1.x, hv.x, z1a); z1b = dot2f16(r1.y, hv.y, z1b);
            z1a = dot2f16(r1.z, hv.z, z1a); z1b = dot2f16(r1.w, hv.w, z1b);
        }
        // LDS part (kk 24..31): lanes read consecutive 16B chunks
#pragma unroll
        for (int j = 0; j < KKLDS; ++j) {
            uint4 hv = hp[KKREG + j];
            uint4 r0 = sh_rec[j * 1024 + g0];
            uint4 r1 = sh_rec[j * 1024 + g1];
            z0a = dot2f16(r0.x, hv.x, z0a); z0b = dot2f16(r0.y, hv.y, z0b);
            z0a = dot2f16(r0.z, hv.z, z0a); z0b = dot2f16(r0.w, hv.w, z0b);
            z1a = dot2f16(r1.x, hv.x, z1a); z1b = dot2f16(r1.y, hv.y, z1b);
            z1a = dot2f16(r1.z, hv.z, z1a); z1b = dot2f16(r1.w, hv.w, z1b);
        }

        float z0 = z0a + z0b + xz0;    // gate i (hi=0) or c (hi=1)
        float z1 = z1a + z1b + xz1;    // gate f (hi=0) or o (hi=1)

        // register-only exchange with the partner half-wave (lane ^ 32)
        float zx0 = __shfl_xor(z0, 32);
        float zx1 = __shfl_xor(z1, 32);
        float zi = hi ? zx0 : z0;
        float zf = hi ? zx1 : z1;
        float zc = hi ? z0 : zx0;
        float zo = hi ? z1 : zx1;

        // gates — both halves compute identical c/h (redundant, cheap, divergence-free)
        float ig = sigmoidf(zi);
        float fg = sigmoidf(zf);
        float og = sigmoidf(zo);
        float cc = fmaxf(zc, 0.f);
        c = fg * c + ig * cc;
        float h = og * fmaxf(c, 0.f);
        if (hi == 0) sh_h[p ^ 1][col] = (_Float16)h;           // write NEXT buffer

        pl0 = fmaf(h, wv.x * wsel, pl0);   // wsel=0 on hi=1 lanes (no double count)
        pl1 = fmaf(h, wv.y * wsel, pl1);

        __syncthreads();                                       // new h visible
        p ^= 1;
    }

    // reduction: contributions live in lanes 0..31 of every wave (hi lanes are 0)
#pragma unroll
    for (int off = 32; off > 0; off >>= 1) {
        pl0 += __shfl_down(pl0, off);
        pl1 += __shfl_down(pl1, off);
    }
    if (lane == 0) {
        rbuf[w] = pl0; rbuf[8 + w] = pl1;
    }
    __syncthreads();
    if (tid == 0) {
        float t0 = 0.f, t1 = 0.f;
#pragma unroll
        for (int i = 0; i < 8; ++i) { t0 += rbuf[i]; t1 += rbuf[8 + i]; }
        atomicAdd(&out[b * 2 + 0], t0);
        atomicAdd(&out[b * 2 + 1], t1);
    }
    if (dir == 0 && tid < 2) atomicAdd(&out[b * 2 + tid], bd[tid]);
}

// ---------------- launch ----------------
extern "C" void kernel_launch(void* const* d_in, const int* in_sizes, int n_in,
                              void* d_out, int out_size, void* d_ws, size_t ws_size,
                              hipStream_t stream) {
    const float* x        = (const float*)d_in[0];
    const float* kernel_f = (const float*)d_in[1];
    const float* rec_f    = (const float*)d_in[2];
    const float* bias_f   = (const float*)d_in[3];
    const float* kernel_b = (const float*)d_in[4];
    const float* rec_b    = (const float*)d_in[5];
    const float* bias_b   = (const float*)d_in[6];
    const float* Wd       = (const float*)d_in[7];
    const float* bd       = (const float*)d_in[8];
    float* out = (float*)d_out;

    // workspace layout
    char* w = (char*)d_ws;
    __hip_bfloat16* xz  = (__hip_bfloat16*)w;                       // 2*32768*1024*2 = 134217728
    __hip_bfloat16* xbf = (__hip_bfloat16*)(w + 134217728);         // 64*512*768*2   = 50331648
    __hip_bfloat16* kT  = (__hip_bfloat16*)(w + 184549376);         // 2*1024*768*2   = 3145728
    unsigned int*  recQ = (unsigned int*) (w + 187695104);          // 2*32*1024*16   = 1048576

    // prep
    int nx = B_ * S_ * E_;
    cast_x_kernel<<<nx / (256 * 4), 256, 0, stream>>>(x, xbf, nx);
    prep_kT_kernel<<<dim3((E_ * G_) / 256, 2), 256, 0, stream>>>(kernel_f, kernel_b, kT);
    prep_recQ_kernel<<<dim3(131072 / 256, 2), 256, 0, stream>>>(rec_f, rec_b, recQ);

    // xz GEMM: grid (N/128, M/128, dirs)
    gemm_xz_kernel<<<dim3(G_ / TN, MROWS / TM, 2), 256, 0, stream>>>(xbf, kT, bias_f, bias_b, xz);

    // zero logits, then scan accumulates
    hipMemsetAsync(d_out, 0, (size_t)out_size * sizeof(float), stream);
    scan_kernel<<<dim3(B_, 2), 512, 0, stream>>>(xz, (const uint4*)recQ, Wd, bd, out);
}